// Round 1
// baseline (1146.722 us; speedup 1.0000x reference)
//
#include <hip/hip_runtime.h>

// ---- problem constants ----
#define T_LEN   240
#define B_SZ    8
#define NFILT   2560
#define KD      9216          // 96*96
#define M_DIM   1920          // B*T
#define N_DIM   5120          // 2*NF (sin | cos)
#define PAD_L   8

typedef unsigned short u16;
typedef __attribute__((ext_vector_type(8))) __bf16 bf16x8;
typedef __attribute__((ext_vector_type(4))) float  f32x4;

// ---------- fp32 -> (hi,lo) bf16 split, RNE both halves ----------
__device__ __forceinline__ u16 f2bf_rne(float f) {
    unsigned u = __float_as_uint(f);
    u += 0x7FFFu + ((u >> 16) & 1u);
    return (u16)(u >> 16);
}

__global__ void split_kernel(const float* __restrict__ src,
                             u16* __restrict__ hi, u16* __restrict__ lo, int n4) {
    int i = blockIdx.x * 256 + threadIdx.x;
    if (i >= n4) return;
    const float4 v = ((const float4*)src)[i];
    float vv[4] = {v.x, v.y, v.z, v.w};
    u16 hh[4], ll[4];
#pragma unroll
    for (int j = 0; j < 4; ++j) {
        unsigned u = __float_as_uint(vv[j]);
        unsigned r = u + 0x7FFFu + ((u >> 16) & 1u);
        u16 hb = (u16)(r >> 16);
        float hf = __uint_as_float((unsigned)hb << 16);
        hh[j] = hb;
        ll[j] = f2bf_rne(vv[j] - hf);   // residual exact in fp32, then RNE
    }
    ushort4 h, l;
    h.x = hh[0]; h.y = hh[1]; h.z = hh[2]; h.w = hh[3];
    l.x = ll[0]; l.y = ll[1]; l.z = ll[2]; l.w = ll[3];
    ((ushort4*)hi)[i] = h;
    ((ushort4*)lo)[i] = l;
}

// ---------- async global->LDS, 16B per lane ----------
__device__ __forceinline__ void glds16(const u16* gp, __bf16* lp) {
    __builtin_amdgcn_global_load_lds(
        (const __attribute__((address_space(1))) void*)gp,
        (__attribute__((address_space(3))) void*)lp, 16, 0, 0);
}

// ---------- bf16x3 split GEMM: C = Ah*Bh + Ah*Bl + Al*Bh ----------
// A = x splits (M=1920 x K=9216), B^T = w splits (N=5120 x K=9216), C = g (M x N) fp32
__global__ __launch_bounds__(256) void gemm_split_kernel(
    const u16* __restrict__ xh, const u16* __restrict__ xl,
    const u16* __restrict__ wh, const u16* __restrict__ wl,
    float* __restrict__ g) {

    __shared__ __align__(16) __bf16 sAh[128 * 32];
    __shared__ __align__(16) __bf16 sAl[128 * 32];
    __shared__ __align__(16) __bf16 sBh[128 * 32];
    __shared__ __align__(16) __bf16 sBl[128 * 32];

    const int tid = threadIdx.x;
    const int l   = tid & 63;
    const int w   = tid >> 6;
    const int m0  = (blockIdx.x / 40) * 128;   // 15 m-tiles
    const int n0  = (blockIdx.x % 40) * 128;   // 40 n-tiles

    // staging: tile[128][32] bf16 row-major; wave w covers 1024B chunks,
    // lane l writes LDS base + l*16 (global_load_lds hw layout)
    const int srow = w * 16 + (l >> 2);        // 0..63 (round 0), +64 (round 1)
    const int skc  = (l & 3) * 8;              // k element offset within BK=32
    const size_t aOff0 = (size_t)(m0 + srow) * KD + skc;
    const size_t aOff1 = aOff0 + (size_t)64 * KD;
    const size_t bOff0 = (size_t)(n0 + srow) * KD + skc;
    const size_t bOff1 = bOff0 + (size_t)64 * KD;
    const int ldsOff0 = srow * 32 + skc;
    const int ldsOff1 = ldsOff0 + 64 * 32;

    // compute mapping: wave (wr,wc) owns 64x64, 4x4 tiles of 16x16x32
    const int wr = (w >> 1) * 64;
    const int wc = (w & 1) * 64;
    const int foff = (l & 15) * 32 + (l >> 4) * 8;  // frag: m/n = l&15, k-quad = l>>4

    f32x4 acc[4][4];
#pragma unroll
    for (int i = 0; i < 4; ++i)
#pragma unroll
        for (int j = 0; j < 4; ++j) {
            f32x4 z = {0.f, 0.f, 0.f, 0.f};
            acc[i][j] = z;
        }

    for (int kt = 0; kt < KD; kt += 32) {
        glds16(xh + aOff0 + kt, &sAh[ldsOff0]);
        glds16(xh + aOff1 + kt, &sAh[ldsOff1]);
        glds16(xl + aOff0 + kt, &sAl[ldsOff0]);
        glds16(xl + aOff1 + kt, &sAl[ldsOff1]);
        glds16(wh + bOff0 + kt, &sBh[ldsOff0]);
        glds16(wh + bOff1 + kt, &sBh[ldsOff1]);
        glds16(wl + bOff0 + kt, &sBl[ldsOff0]);
        glds16(wl + bOff1 + kt, &sBl[ldsOff1]);
        __syncthreads();

        bf16x8 bh[4], blo[4];
#pragma unroll
        for (int tc = 0; tc < 4; ++tc) {
            bh[tc]  = *(const bf16x8*)&sBh[(wc + tc * 16) * 32 + foff];
            blo[tc] = *(const bf16x8*)&sBl[(wc + tc * 16) * 32 + foff];
        }
#pragma unroll
        for (int tr = 0; tr < 4; ++tr) {
            bf16x8 ah  = *(const bf16x8*)&sAh[(wr + tr * 16) * 32 + foff];
            bf16x8 alo = *(const bf16x8*)&sAl[(wr + tr * 16) * 32 + foff];
#pragma unroll
            for (int tc = 0; tc < 4; ++tc) {
                acc[tr][tc] = __builtin_amdgcn_mfma_f32_16x16x32_bf16(ah,  bh[tc],  acc[tr][tc], 0, 0, 0);
                acc[tr][tc] = __builtin_amdgcn_mfma_f32_16x16x32_bf16(ah,  blo[tc], acc[tr][tc], 0, 0, 0);
                acc[tr][tc] = __builtin_amdgcn_mfma_f32_16x16x32_bf16(alo, bh[tc],  acc[tr][tc], 0, 0, 0);
            }
        }
        __syncthreads();
    }

    // epilogue: C/D layout col = l&15, row = (l>>4)*4 + reg  (m89/m91-verified)
    const int crow = (l >> 4) * 4;
    const int ccol = l & 15;
#pragma unroll
    for (int tr = 0; tr < 4; ++tr)
#pragma unroll
        for (int tc = 0; tc < 4; ++tc) {
            const int row = m0 + wr + tr * 16 + crow;
            const int col = n0 + wc + tc * 16 + ccol;
            float* dst = g + (size_t)row * N_DIM + col;
#pragma unroll
            for (int r = 0; r < 4; ++r)
                dst[(size_t)r * N_DIM] = acc[tr][tc][r];
        }
}

// ---------- depthwise temporal conv (cross-corr, pad 8/7) + energy ----------
// out[b,t,f] = log(sqrt(rs^2 + rc^2) + 1e-5)
// rs = sum_j gs[t+j-8]*wtc[j] + gc[t+j-8]*wts[j]
// rc = sum_j gc[t+j-8]*wtc[j] - gs[t+j-8]*wts[j]
__global__ void conv_energy_kernel(const float* __restrict__ g,
                                   const float* __restrict__ wts,
                                   const float* __restrict__ wtc,
                                   float* __restrict__ out) {
    const int idx = blockIdx.x * 256 + threadIdx.x;
    const int f  = idx % NFILT;
    const int bt = idx / NFILT;
    const int t  = bt % T_LEN;
    const int b  = bt / T_LEN;
    const float* grow = g + (size_t)b * T_LEN * N_DIM + f;
    const float* pwc = wtc + f * 16;
    const float* pws = wts + f * 16;
    float s = 0.f, c = 0.f;
#pragma unroll
    for (int j = 0; j < 16; ++j) {
        const int tt = t + j - PAD_L;
        if (tt >= 0 && tt < T_LEN) {   // uniform across the block (f varies, t fixed)
            const float gs = grow[(size_t)tt * N_DIM];
            const float gc = grow[(size_t)tt * N_DIM + NFILT];
            const float a = pwc[j], bb = pws[j];
            s += gs * a + gc * bb;
            c += gc * a - gs * bb;
        }
    }
    const float r = sqrtf(s * s + c * c);
    out[idx] = logf(r + 1e-5f);
}

extern "C" void kernel_launch(void* const* d_in, const int* in_sizes, int n_in,
                              void* d_out, int out_size, void* d_ws, size_t ws_size,
                              hipStream_t stream) {
    const float* x   = (const float*)d_in[0];  // (8,240,96,96)
    const float* wss = (const float*)d_in[1];  // (2560,96,96)
    const float* wsc = (const float*)d_in[2];  // (2560,96,96)
    const float* wts = (const float*)d_in[3];  // (2560,16)
    const float* wtc = (const float*)d_in[4];  // (2560,16)
    float* out = (float*)d_out;

    // workspace layout (bytes):
    //   xh: 35,389,440 | xl: 35,389,440 | wh: 94,371,840 | wl: 94,371,840 | g: 39,321,600
    char* ws = (char*)d_ws;
    u16*   xh = (u16*)(ws);
    u16*   xl = (u16*)(ws + 35389440);
    u16*   whi = (u16*)(ws + 70778880);
    u16*   wlo = (u16*)(ws + 165150720);
    float* g   = (float*)(ws + 259522560);

    const int nx4 = 17694720 / 4;   // x floats / 4
    const int nw4 = 23592960 / 4;   // per w_s array floats / 4
    split_kernel<<<(nx4 + 255) / 256, 256, 0, stream>>>(x, xh, xl, nx4);
    split_kernel<<<(nw4 + 255) / 256, 256, 0, stream>>>(wss, whi, wlo, nw4);
    split_kernel<<<(nw4 + 255) / 256, 256, 0, stream>>>(
        wsc, whi + (size_t)NFILT * KD, wlo + (size_t)NFILT * KD, nw4);

    gemm_split_kernel<<<600, 256, 0, stream>>>(xh, xl, whi, wlo, g);

    conv_energy_kernel<<<(B_SZ * T_LEN * NFILT) / 256, 256, 0, stream>>>(g, wts, wtc, out);
}